// Round 3
// baseline (906.753 us; speedup 1.0000x reference)
//
#include <hip/hip_runtime.h>
#include <hip/hip_fp16.h>

#define N_NODES 40000
#define N_EDGES 400000
#define N_GRAPHS 64
#define D1 256      // heads*hid for conv1
#define HIDC 64
#define NHEADS 4
#define EDIM 18
#define EPAD 20     // padded ea_s row stride (16B-aligned rows)
#define OUTF 3

// ---------------- init: zero degree histogram + pool accumulators ----------
__global__ void init_kernel(int* __restrict__ deg, float* __restrict__ pooled,
                            float* __restrict__ cnt) {
    int t = blockIdx.x * 256 + threadIdx.x;
    if (t < N_NODES) deg[t] = 0;
    if (t < N_GRAPHS * HIDC) pooled[t] = 0.f;
    if (t < N_GRAPHS) cnt[t] = 0.f;
}

// ---------------- conv1 low-rank precompute ----------------
// cbuf layout per head h (63 floats at h*63):
//   [0..9)  M[a*3+b] = A_a(h) . B_b(h)   (A = {Wq row0, Wq row1, bq}, B = {Wk row0, Wk row1, bk})
//   [9..63) U[r*18+j] = A_r(h) . We1[j] (h-slice)
__global__ void precompute1(const float* __restrict__ Wq, const float* __restrict__ bq,
                            const float* __restrict__ Wk, const float* __restrict__ bk,
                            const float* __restrict__ We, float* __restrict__ cbuf) {
    int t = threadIdx.x;
    if (t < 36) {
        int h = t / 9, r = t % 9, a = r / 3, b = r % 3;
        const float* A = (a == 0) ? Wq : (a == 1) ? Wq + D1 : bq;
        const float* B = (b == 0) ? Wk : (b == 1) ? Wk + D1 : bk;
        float s = 0.f;
        for (int c = 0; c < 64; ++c) s += A[h * 64 + c] * B[h * 64 + c];
        cbuf[h * 63 + a * 3 + b] = s;
    } else if (t < 252) {
        int i = t - 36;
        int h = i / 54, rr = (i % 54) / 18, j = i % 18;
        const float* A = (rr == 0) ? Wq : (rr == 1) ? Wq + D1 : bq;
        float s = 0.f;
        for (int c = 0; c < 64; ++c) s += A[h * 64 + c] * We[j * D1 + h * 64 + c];
        cbuf[h * 63 + 9 + rr * 18 + j] = s;
    }
}

// ---------------- CSR build ----------------
__global__ void hist_kernel(const int* __restrict__ ei, int* __restrict__ deg) {
    int e = blockIdx.x * 256 + threadIdx.x;
    if (e < N_EDGES) atomicAdd(&deg[ei[N_EDGES + e]], 1);
}

__global__ void scan_kernel(const int* __restrict__ deg, int* __restrict__ row_ptr,
                            int* __restrict__ cursor) {
    __shared__ int sums[1024];
    int t = threadIdx.x;
    const int PER = 40;                      // 1024*40 >= 40000
    int base = t * PER;
    int s = 0;
    for (int i = 0; i < PER; ++i) {
        int idx = base + i;
        if (idx < N_NODES) s += deg[idx];
    }
    sums[t] = s;
    __syncthreads();
    for (int off = 1; off < 1024; off <<= 1) {
        int v = sums[t];
        int w = (t >= off) ? sums[t - off] : 0;
        __syncthreads();
        sums[t] = v + w;
        __syncthreads();
    }
    int run = (t == 0) ? 0 : sums[t - 1];
    for (int i = 0; i < PER; ++i) {
        int idx = base + i;
        if (idx < N_NODES) {
            row_ptr[idx] = run;
            cursor[idx] = run;
            run += deg[idx];
        }
    }
    if (t == 0) row_ptr[N_NODES] = sums[1023];
}

__global__ void scatter_kernel(const int* __restrict__ ei, const float* __restrict__ ea,
                               const float* __restrict__ x, int* __restrict__ cursor,
                               int* __restrict__ src_s, float* __restrict__ ea_s,
                               float2* __restrict__ x_s) {
    int e = blockIdx.x * 256 + threadIdx.x;
    if (e >= N_EDGES) return;
    int src = ei[e], dst = ei[N_EDGES + e];
    int p = atomicAdd(&cursor[dst], 1);
    src_s[p] = src;
    x_s[p] = make_float2(x[src * 2], x[src * 2 + 1]);
    const float* srow = ea + (size_t)e * EDIM;
    float s[EDIM];
    #pragma unroll
    for (int j = 0; j < EDIM; ++j) s[j] = srow[j];
    float4* drow = (float4*)(ea_s + (size_t)p * EPAD);
    drow[0] = make_float4(s[0],  s[1],  s[2],  s[3]);
    drow[1] = make_float4(s[4],  s[5],  s[6],  s[7]);
    drow[2] = make_float4(s[8],  s[9],  s[10], s[11]);
    drow[3] = make_float4(s[12], s[13], s[14], s[15]);
    drow[4] = make_float4(s[16], s[17], 0.f, 0.f);
}

// ---------------- conv1 fused: one thread per (node, head) ----------------
__global__ void conv1_fused(const float* __restrict__ x, const int* __restrict__ row_ptr,
                            const float* __restrict__ ea_s, const float2* __restrict__ x_s,
                            const float* __restrict__ cbuf, float* __restrict__ acc1) {
    __shared__ float cb[252];
    int t = threadIdx.x;
    if (t < 252) cb[t] = cbuf[t];
    __syncthreads();
    int tid = blockIdx.x * 256 + t;          // exactly N*4 threads
    int node = tid >> 2, h = tid & 3;
    const float* c = &cb[h * 63];
    float2 xn = ((const float2*)x)[node];
    float x0 = xn.x, x1 = xn.y;
    float c0 = x0 * c[0] + x1 * c[3] + c[6];
    float c1 = x0 * c[1] + x1 * c[4] + c[7];
    float c2 = x0 * c[2] + x1 * c[5] + c[8];
    float u[EDIM];
    #pragma unroll
    for (int j = 0; j < EDIM; ++j) u[j] = x0 * c[9 + j] + x1 * c[27 + j] + c[45 + j];

    float m = -INFINITY, l = 0.f, s0 = 0.f, s1 = 0.f;
    float sea[EDIM];
    #pragma unroll
    for (int j = 0; j < EDIM; ++j) sea[j] = 0.f;

    int beg = row_ptr[node], end = row_ptr[node + 1];
    for (int p = beg; p < end; ++p) {
        float2 xs = x_s[p];
        const float4* ear4 = (const float4*)(ea_s + (size_t)p * EPAD);
        float4 r0 = ear4[0], r1 = ear4[1], r2 = ear4[2], r3 = ear4[3], r4 = ear4[4];
        float ev[EDIM] = {r0.x,r0.y,r0.z,r0.w, r1.x,r1.y,r1.z,r1.w,
                          r2.x,r2.y,r2.z,r2.w, r3.x,r3.y,r3.z,r3.w, r4.x,r4.y};
        float a = c0 * xs.x + c1 * xs.y + c2;
        #pragma unroll
        for (int j = 0; j < EDIM; ++j) a += ev[j] * u[j];
        a *= 0.125f;                          // 1/sqrt(64)
        float mn = fmaxf(m, a);
        float f  = __expf(m - mn);            // m=-inf first iter -> 0
        float ex = __expf(a - mn);
        l  = l  * f + ex;
        s0 = s0 * f + ex * xs.x;
        s1 = s1 * f + ex * xs.y;
        #pragma unroll
        for (int j = 0; j < EDIM; ++j) sea[j] = sea[j] * f + ex * ev[j];
        m = mn;
    }
    float* o = acc1 + (size_t)tid * 21;
    o[0] = s0; o[1] = s1; o[2] = l;
    #pragma unroll
    for (int j = 0; j < EDIM; ++j) o[3 + j] = sea[j];
}

// ---------------- conv1 finalize: expand accumulators, beta skip, relu ------
__global__ void finalize1(const float* __restrict__ x, const float* __restrict__ acc1,
                          const float* __restrict__ Wv, const float* __restrict__ bv,
                          const float* __restrict__ We, const float* __restrict__ Wskip,
                          const float* __restrict__ bskip, const float* __restrict__ Wbeta,
                          float* __restrict__ h1) {
    __shared__ float red[4];
    int node = blockIdx.x;
    int t = threadIdx.x;                      // = d in [0,256)
    int h = t >> 6;
    const float* a = acc1 + (size_t)(node * 4 + h) * 21;
    float s0 = a[0], s1 = a[1], l = a[2];
    float o = s0 * Wv[t] + s1 * Wv[D1 + t] + l * bv[t];
    #pragma unroll
    for (int j = 0; j < EDIM; ++j) o += a[3 + j] * We[j * D1 + t];
    o /= (l + 1e-16f);
    float x0 = x[node * 2], x1 = x[node * 2 + 1];
    float xr = x0 * Wskip[t] + x1 * Wskip[D1 + t] + bskip[t];
    float part = o * Wbeta[t] + xr * Wbeta[D1 + t] + (o - xr) * Wbeta[2 * D1 + t];
    #pragma unroll
    for (int off = 32; off; off >>= 1) part += __shfl_xor(part, off);
    if ((t & 63) == 0) red[t >> 6] = part;
    __syncthreads();
    float tot = red[0] + red[1] + red[2] + red[3];
    float beta = 1.f / (1.f + __expf(-tot));
    h1[(size_t)node * D1 + t] = fmaxf(beta * xr + (1.f - beta) * o, 0.f);
}

// ---------------- conv2: node linears (256 -> 64 x4), 16 nodes/block --------
__global__ void node_linear2(const float* __restrict__ h1,
                             const float* __restrict__ Wq, const float* __restrict__ bq,
                             const float* __restrict__ Wk, const float* __restrict__ bk,
                             const float* __restrict__ Wv, const float* __restrict__ bv,
                             const float* __restrict__ Ws, const float* __restrict__ bs,
                             float* __restrict__ q2, float* __restrict__ k2,
                             float* __restrict__ v2, float* __restrict__ xr2) {
    __shared__ float4 hb4[16][64];
    int nb = blockIdx.x * 16;
    int t = threadIdx.x;
    const float4* src = (const float4*)(h1 + (size_t)nb * D1);
    #pragma unroll
    for (int i = 0; i < 4; ++i) ((float4*)hb4)[t + i * 256] = src[t + i * 256];
    __syncthreads();
    int m = t >> 6, d = t & 63;
    const float* W; const float* b; float* outp;
    if (m == 0)      { W = Wq; b = bq; outp = q2; }
    else if (m == 1) { W = Wk; b = bk; outp = k2; }
    else if (m == 2) { W = Wv; b = bv; outp = v2; }
    else             { W = Ws; b = bs; outp = xr2; }
    float acc[16];
    #pragma unroll
    for (int i = 0; i < 16; ++i) acc[i] = b[d];
    for (int k4 = 0; k4 < 64; ++k4) {
        float w0 = W[(k4 * 4 + 0) * 64 + d];
        float w1 = W[(k4 * 4 + 1) * 64 + d];
        float w2 = W[(k4 * 4 + 2) * 64 + d];
        float w3 = W[(k4 * 4 + 3) * 64 + d];
        #pragma unroll
        for (int i = 0; i < 16; ++i) {
            float4 hv = hb4[i][k4];
            acc[i] += hv.x * w0 + hv.y * w1 + hv.z * w2 + hv.w * w3;
        }
    }
    #pragma unroll
    for (int i = 0; i < 16; ++i)
        outp[(size_t)(nb + i) * 64 + d] = acc[i];
}

// ---------------- build e2 = ea_s @ We2 (fp16, CSR edge order) --------------
__global__ void build_e2(const float* __restrict__ ea_s, const float* __restrict__ We2,
                         __half* __restrict__ e2) {
    __shared__ float w2[EDIM * 64];
    int t = threadIdx.x;
    for (int i = t; i < EDIM * 64; i += 256) w2[i] = We2[i];
    __syncthreads();
    int p = blockIdx.x * 4 + (t >> 6);        // exactly E edges
    int lane = t & 63;
    float r = (lane < EPAD) ? ea_s[(size_t)p * EPAD + lane] : 0.f;
    float e = 0.f;
    #pragma unroll
    for (int j = 0; j < EDIM; ++j) e += __shfl(r, j) * w2[j * 64 + lane];
    e2[(size_t)p * 64 + lane] = __float2half(e);
}

// ---------------- conv2 fused: wave per node — attn + beta + pool -----------
__global__ void conv2_fused(const int* __restrict__ row_ptr, const int* __restrict__ src_s,
                            const __half* __restrict__ e2, const float* __restrict__ q2,
                            const float* __restrict__ k2, const float* __restrict__ v2,
                            const float* __restrict__ xr2, const float* __restrict__ Wb2,
                            const int* __restrict__ batch,
                            float* __restrict__ pooled, float* __restrict__ cnt) {
    int t = threadIdx.x;
    int node = blockIdx.x * 4 + (t >> 6);     // exactly N nodes
    int lane = t & 63;
    float q = q2[(size_t)node * 64 + lane];
    float m = -INFINITY, l = 0.f, acc = 0.f;
    int p = row_ptr[node], end = row_ptr[node + 1];
    if ((end - p) & 1) {                      // odd-degree head: first edge alone
        int src = src_s[p];
        float e = __half2float(e2[(size_t)p * 64 + lane]);
        float kj = k2[(size_t)src * 64 + lane] + e;
        float d = q * kj;
        #pragma unroll
        for (int off = 32; off; off >>= 1) d += __shfl_xor(d, off);
        m = d * 0.125f;
        l = 1.f;
        acc = v2[(size_t)src * 64 + lane] + e;
        ++p;
    }
    for (; p < end; p += 2) {
        int s0 = src_s[p], s1 = src_s[p + 1];
        float e0 = __half2float(e2[(size_t)p * 64 + lane]);
        float e1 = __half2float(e2[(size_t)(p + 1) * 64 + lane]);
        float kj0 = k2[(size_t)s0 * 64 + lane] + e0;
        float kj1 = k2[(size_t)s1 * 64 + lane] + e1;
        float vv0 = v2[(size_t)s0 * 64 + lane] + e0;
        float vv1 = v2[(size_t)s1 * 64 + lane] + e1;
        float d0 = q * kj0, d1 = q * kj1;
        #pragma unroll
        for (int off = 32; off; off >>= 1) {
            d0 += __shfl_xor(d0, off);
            d1 += __shfl_xor(d1, off);
        }
        float a0 = d0 * 0.125f, a1 = d1 * 0.125f;
        float mn = fmaxf(m, fmaxf(a0, a1));
        float f  = __expf(m - mn);
        float x0 = __expf(a0 - mn);
        float x1 = __expf(a1 - mn);
        l   = l   * f + x0 + x1;
        acc = acc * f + x0 * vv0 + x1 * vv1;
        m = mn;
    }
    float o = acc / (l + 1e-16f);
    float xr = xr2[(size_t)node * 64 + lane];
    float part = o * Wb2[lane] + xr * Wb2[64 + lane] + (o - xr) * Wb2[128 + lane];
    #pragma unroll
    for (int off = 32; off; off >>= 1) part += __shfl_xor(part, off);
    float beta = 1.f / (1.f + __expf(-part));
    float hh = fmaxf(beta * xr + (1.f - beta) * o, 0.f);
    int g = batch[node];
    atomicAdd(&pooled[g * 64 + lane], hh);
    if (lane == 0) atomicAdd(&cnt[g], 1.f);
}

// ---------------- final linear ----------------
__global__ void final_lin(const float* __restrict__ pooled, const float* __restrict__ cnt,
                          const float* __restrict__ Wlin, const float* __restrict__ blin,
                          float* __restrict__ out) {
    int t = threadIdx.x;
    if (t >= N_GRAPHS * OUTF) return;
    int g = t / OUTF, o = t % OUTF;
    float inv = 1.f / fmaxf(cnt[g], 1.f);
    float acc = 0.f;
    for (int kk = 0; kk < HIDC; ++kk) acc += pooled[g * 64 + kk] * Wlin[kk * OUTF + o];
    out[t] = acc * inv + blin[o];
}

extern "C" void kernel_launch(void* const* d_in, const int* in_sizes, int n_in,
                              void* d_out, int out_size, void* d_ws, size_t ws_size,
                              hipStream_t stream) {
    const float* x      = (const float*)d_in[0];
    const int*   ei     = (const int*)d_in[1];
    const float* ea     = (const float*)d_in[2];
    const int*   batch  = (const int*)d_in[3];
    const float* Wq1    = (const float*)d_in[4];  const float* bq1    = (const float*)d_in[5];
    const float* Wk1    = (const float*)d_in[6];  const float* bk1    = (const float*)d_in[7];
    const float* Wv1    = (const float*)d_in[8];  const float* bv1    = (const float*)d_in[9];
    const float* We1    = (const float*)d_in[10];
    const float* Wskip1 = (const float*)d_in[11]; const float* bskip1 = (const float*)d_in[12];
    const float* Wbeta1 = (const float*)d_in[13];
    const float* Wq2    = (const float*)d_in[14]; const float* bq2    = (const float*)d_in[15];
    const float* Wk2    = (const float*)d_in[16]; const float* bk2    = (const float*)d_in[17];
    const float* Wv2    = (const float*)d_in[18]; const float* bv2    = (const float*)d_in[19];
    const float* We2    = (const float*)d_in[20];
    const float* Wskip2 = (const float*)d_in[21]; const float* bskip2 = (const float*)d_in[22];
    const float* Wbeta2 = (const float*)d_in[23];
    const float* Wlin   = (const float*)d_in[24]; const float* blin   = (const float*)d_in[25];

    float* f = (float*)d_ws;
    float* q2     = f;                                     // N*64
    float* k2     = q2 + (size_t)N_NODES * HIDC;
    float* v2     = k2 + (size_t)N_NODES * HIDC;
    float* xr2    = v2 + (size_t)N_NODES * HIDC;
    float* ea_s   = xr2 + (size_t)N_NODES * HIDC;          // E*20 (padded rows)
    float* x_sf   = ea_s + (size_t)N_EDGES * EPAD;         // E*2 (float2)
    float* pooled = x_sf + (size_t)N_EDGES * 2;            // G*64
    float* cnt    = pooled + N_GRAPHS * HIDC;              // G
    float* cbuf   = cnt + N_GRAPHS;                        // 252
    int* deg      = (int*)(cbuf + 252);                    // N
    int* row_ptr  = deg + N_NODES;                         // N+1
    int* cursor   = row_ptr + N_NODES + 1;                 // N
    int* src_s    = cursor + N_NODES;                      // E
    float* h1     = (float*)(src_s + N_EDGES);             // N*256
    float* acc1   = h1 + (size_t)N_NODES * D1;             // N*4*21 (right after h1)
    // e2 (fp16, E*64 = 51.2 MB) aliases [h1, acc1] (54.4 MB) — both dead by then
    __half* e2    = (__half*)h1;
    float2* x_s   = (float2*)x_sf;

    const int EB = (N_EDGES + 255) / 256;
    const int NB = (N_NODES + 255) / 256;

    init_kernel<<<NB, 256, 0, stream>>>(deg, pooled, cnt);
    precompute1<<<1, 256, 0, stream>>>(Wq1, bq1, Wk1, bk1, We1, cbuf);
    hist_kernel<<<EB, 256, 0, stream>>>(ei, deg);
    scan_kernel<<<1, 1024, 0, stream>>>(deg, row_ptr, cursor);
    scatter_kernel<<<EB, 256, 0, stream>>>(ei, ea, x, cursor, src_s, ea_s, x_s);

    conv1_fused<<<(N_NODES * 4) / 256, 256, 0, stream>>>(x, row_ptr, ea_s, x_s, cbuf, acc1);
    finalize1<<<N_NODES, 256, 0, stream>>>(x, acc1, Wv1, bv1, We1, Wskip1, bskip1, Wbeta1, h1);

    node_linear2<<<N_NODES / 16, 256, 0, stream>>>(h1, Wq2, bq2, Wk2, bk2, Wv2, bv2,
                                                   Wskip2, bskip2, q2, k2, v2, xr2);
    build_e2<<<N_EDGES / 4, 256, 0, stream>>>(ea_s, We2, e2);
    conv2_fused<<<N_NODES / 4, 256, 0, stream>>>(row_ptr, src_s, e2, q2, k2, v2, xr2,
                                                 Wbeta2, batch, pooled, cnt);
    final_lin<<<1, 256, 0, stream>>>(pooled, cnt, Wlin, blin, (float*)d_out);
}